// Round 1
// baseline (237.245 us; speedup 1.0000x reference)
//
#include <hip/hip_runtime.h>
#include <math.h>

// Problem constants (fixed by the reference).
#define Bsz 64
#define Ssz 14
#define Isz 32
#define Csz 10
#define Psz 4
#define Dsz 16
#define Nsz (Ssz*Ssz*Isz)   // 6272
#define EPSF 1e-9f

// ---------------------------------------------------------------------------
// M-step kernel: one block per (b,c). Threads stride over n, accumulating
//   S0 = sum_n w_n,  S1[d] = sum_n w_n * v[d],  S2[d] = sum_n w_n * v[d]^2
// where w_n = rr_p[b,c,n] (or act[n]/C on the uniform first iteration) and
// v = vote[n,c,:] recomputed on the fly (pose[n] 4x4 @ W[i,c] 4x4 + coords).
// Then wave butterfly + cross-wave LDS reduction; thread 0 computes
// mean/var/stdv/cost/o_act and writes the 33 params for the next E-step.
// Finalize is fused here because cost/o_act have no cross-c coupling.
// ---------------------------------------------------------------------------
__global__ __launch_bounds__(256) void m_step_kernel(
    const float* __restrict__ pose,     // [B][N][16]
    const float* __restrict__ act,      // [B][N]
    const float* __restrict__ w,        // [I][C][16]
    const float* __restrict__ beta_v,   // [C]
    const float* __restrict__ beta_a,   // [C]
    const float* __restrict__ rr_p,     // [B][C][N]
    float* __restrict__ params,         // [B][C][33] : mean[16], invdenom[16], K
    float* __restrict__ out,            // [B][C][16] then [B][C]
    float inv_temp, int uniform, int final_it)
{
    const int bc = blockIdx.x;
    const int b = bc / Csz, c = bc % Csz;
    const int tid = threadIdx.x;

    __shared__ float Wc[Isz*17];        // W[i][c][qr], stride 17 -> conflict-free
    __shared__ float red[4][33];

    for (int t = tid; t < Isz*Dsz; t += 256) {
        int i = t >> 4, qr = t & 15;
        Wc[i*17 + qr] = w[(i*Csz + c)*Dsz + qr];
    }
    __syncthreads();

    float s0 = 0.f;
    float s1[Dsz], s2[Dsz];
#pragma unroll
    for (int d = 0; d < Dsz; ++d) { s1[d] = 0.f; s2[d] = 0.f; }

    const float* poseb = pose + (size_t)b * Nsz * Dsz;
    const float* actb  = act  + (size_t)b * Nsz;
    const float* rrb   = rr_p + ((size_t)b * Csz + c) * Nsz;

    for (int n = tid; n < Nsz; n += 256) {
        const float4* pp = reinterpret_cast<const float4*>(poseb + (size_t)n * Dsz);
        float4 a0 = pp[0], a1 = pp[1], a2 = pp[2], a3 = pp[3];
        float p[16] = {a0.x,a0.y,a0.z,a0.w, a1.x,a1.y,a1.z,a1.w,
                       a2.x,a2.y,a2.z,a2.w, a3.x,a3.y,a3.z,a3.w};
        int i  = n & (Isz-1);
        int hw = n >> 5;
        int wcol = hw % Ssz, hrow = hw / Ssz;
        float wgt = uniform ? (actb[n] * (1.0f/Csz)) : rrb[n];

        const float* Wi = &Wc[i*17];
        float v[16];
#pragma unroll
        for (int pr = 0; pr < 4; ++pr) {
#pragma unroll
            for (int r = 0; r < 4; ++r) {
                v[pr*4+r] = p[pr*4+0]*Wi[0*4+r] + p[pr*4+1]*Wi[1*4+r]
                          + p[pr*4+2]*Wi[2*4+r] + p[pr*4+3]*Wi[3*4+r];
            }
        }
        v[0] += (hrow + 0.5f) * (1.0f/Ssz);   // coordinate addition (h on elem 0)
        v[1] += (wcol + 0.5f) * (1.0f/Ssz);   // (w on elem 1)

        s0 += wgt;
#pragma unroll
        for (int d = 0; d < Dsz; ++d) {
            float wv = wgt * v[d];
            s1[d] += wv;
            s2[d] += wv * v[d];
        }
    }

    // 64-lane wave butterfly reduction
#pragma unroll
    for (int m = 32; m >= 1; m >>= 1) {
        s0 += __shfl_xor(s0, m);
#pragma unroll
        for (int d = 0; d < Dsz; ++d) {
            s1[d] += __shfl_xor(s1[d], m);
            s2[d] += __shfl_xor(s2[d], m);
        }
    }
    const int wave = tid >> 6, lane = tid & 63;
    if (lane == 0) {
        red[wave][0] = s0;
#pragma unroll
        for (int d = 0; d < Dsz; ++d) { red[wave][1+d] = s1[d]; red[wave][17+d] = s2[d]; }
    }
    __syncthreads();

    if (tid == 0) {
        float S0 = red[0][0] + red[1][0] + red[2][0] + red[3][0];
        float sumlog = 0.f;
        float mean[16], invd[16];
#pragma unroll
        for (int d = 0; d < Dsz; ++d) {
            float S1 = red[0][1+d]  + red[1][1+d]  + red[2][1+d]  + red[3][1+d];
            float S2 = red[0][17+d] + red[1][17+d] + red[2][17+d] + red[3][17+d];
            float mn  = S1 / S0;
            float var = fmaxf(S2 / S0 - mn*mn, 0.f);   // one-pass variance, clamped
            float stdv = sqrtf(var);
            sumlog += logf(stdv + EPSF);
            mean[d] = mn;
            invd[d] = 1.f / (2.f*var + EPSF);
        }
        float cost = S0 * (16.f * beta_v[c] + sumlog);
        float oact = 1.f / (1.f + expf(-inv_temp * (beta_a[c] - cost)));

        float* prm = params + (size_t)(b*Csz + c) * 33;
#pragma unroll
        for (int d = 0; d < Dsz; ++d) { prm[d] = mean[d]; prm[16+d] = invd[d]; }
        prm[32] = logf(oact + EPSF) - sumlog;   // K[c] for the E-step

        if (final_it) {
            float* om = out + (size_t)(b*Csz + c) * Dsz;
#pragma unroll
            for (int d = 0; d < Dsz; ++d) om[d] = mean[d];
            out[Bsz*Csz*Dsz + b*Csz + c] = oact;
        }
    }
}

// ---------------------------------------------------------------------------
// E-step kernel: thread per (b,n). Recompute all C*16 votes, form
// zz[c] = K[c] - sum_d (v-mean)^2 * invdenom, softmax over c, write
// rr_p[b][c][n] = softmax(zz)[c] * act[n]  (layout -> coalesced E writes
// AND coalesced M reads).
// ---------------------------------------------------------------------------
__global__ __launch_bounds__(256) void e_step_kernel(
    const float* __restrict__ pose,     // [B][N][16]
    const float* __restrict__ act,      // [B][N]
    const float* __restrict__ w,        // [I][C][16]
    const float* __restrict__ params,   // [B][C][33]
    float* __restrict__ rr_p)           // [B][C][N]
{
    const int b = blockIdx.y;
    const int tid = threadIdx.x;
    const int n = blockIdx.x * 256 + tid;

    __shared__ float Wl[Isz*161];       // W[i][c*16+qr], stride 161 -> conflict-free
    __shared__ float prm[Csz*33];

    for (int t = tid; t < Isz*Csz*Dsz; t += 256) {
        int i = t / (Csz*Dsz);
        int rest = t - i*(Csz*Dsz);
        Wl[i*161 + rest] = w[t];
    }
    for (int t = tid; t < Csz*33; t += 256)
        prm[t] = params[(size_t)b*Csz*33 + t];
    __syncthreads();

    if (n >= Nsz) return;

    const float4* pp = reinterpret_cast<const float4*>(pose + ((size_t)b * Nsz + n) * Dsz);
    float4 a0 = pp[0], a1 = pp[1], a2 = pp[2], a3 = pp[3];
    float p[16] = {a0.x,a0.y,a0.z,a0.w, a1.x,a1.y,a1.z,a1.w,
                   a2.x,a2.y,a2.z,a2.w, a3.x,a3.y,a3.z,a3.w};
    float a = act[(size_t)b*Nsz + n];
    const int i = n & (Isz-1);
    const int hw = n >> 5;
    const int wcol = hw % Ssz, hrow = hw / Ssz;
    const float ch = (hrow + 0.5f) * (1.0f/Ssz);
    const float cw = (wcol + 0.5f) * (1.0f/Ssz);

    float zz[Csz];
#pragma unroll
    for (int c = 0; c < Csz; ++c) {
        const float* Wi = &Wl[i*161 + c*16];
        const float* pc = &prm[c*33];       // broadcast reads (same addr all lanes)
        float quad = 0.f;
#pragma unroll
        for (int pr = 0; pr < 4; ++pr) {
#pragma unroll
            for (int r = 0; r < 4; ++r) {
                float v = p[pr*4+0]*Wi[0*4+r] + p[pr*4+1]*Wi[1*4+r]
                        + p[pr*4+2]*Wi[2*4+r] + p[pr*4+3]*Wi[3*4+r];
                const int d = pr*4 + r;
                if (d == 0) v += ch;
                if (d == 1) v += cw;
                float dv = v - pc[d];
                quad += dv * dv * pc[16+d];
            }
        }
        zz[c] = pc[32] - quad;
    }

    float zmax = zz[0];
#pragma unroll
    for (int c = 1; c < Csz; ++c) zmax = fmaxf(zmax, zz[c]);
    float zsum = 0.f;
#pragma unroll
    for (int c = 0; c < Csz; ++c) { zz[c] = expf(zz[c] - zmax); zsum += zz[c]; }
    const float sc = a / zsum;
#pragma unroll
    for (int c = 0; c < Csz; ++c)
        rr_p[((size_t)b*Csz + c)*Nsz + n] = zz[c] * sc;
}

// ---------------------------------------------------------------------------
// 3 routing iterations = M0(uniform), E1, M1, E2, M2(final outputs).
// Workspace: rr_p [B][C][N] (16.06 MB) + params [B][C][33] (84 KB).
// Everything in ws is written before it is read within this launch.
// ---------------------------------------------------------------------------
extern "C" void kernel_launch(void* const* d_in, const int* in_sizes, int n_in,
                              void* d_out, int out_size, void* d_ws, size_t ws_size,
                              hipStream_t stream)
{
    const float* pose = (const float*)d_in[0];
    const float* act  = (const float*)d_in[1];
    const float* w    = (const float*)d_in[2];
    const float* bv   = (const float*)d_in[3];
    const float* ba   = (const float*)d_in[4];
    float* out = (float*)d_out;

    float* rr_p   = (float*)d_ws;
    float* params = rr_p + (size_t)Bsz*Csz*Nsz;

    dim3 egrid((Nsz + 255)/256, Bsz);

    // it=0, inv_temp=1, uniform rr
    m_step_kernel<<<Bsz*Csz, 256, 0, stream>>>(pose, act, w, bv, ba, rr_p, params, out, 1.0f, 1, 0);
    // it=1
    e_step_kernel<<<egrid, 256, 0, stream>>>(pose, act, w, params, rr_p);
    m_step_kernel<<<Bsz*Csz, 256, 0, stream>>>(pose, act, w, bv, ba, rr_p, params, out, 2.0f, 0, 0);
    // it=2
    e_step_kernel<<<egrid, 256, 0, stream>>>(pose, act, w, params, rr_p);
    m_step_kernel<<<Bsz*Csz, 256, 0, stream>>>(pose, act, w, bv, ba, rr_p, params, out, 3.0f, 0, 1);
}